// Round 1
// baseline (309.895 us; speedup 1.0000x reference)
//
#include <hip/hip_runtime.h>

#define THREADS 256
#define IMGS 8

// s_w packed offsets
#define O_C1W 0
#define O_C1B 150
#define O_FSW 156
#define O_SCW 231
#define O_THW 331
#define O_FOW 431
#define O_GB  581
#define O_C5B 585
#define O_F6B 705
#define O_OUTW 789
#define O_OUTB 1629
#define SW_SIZE 1648

__device__ __forceinline__ float fast_tanh(float v) {
    float xc = fminf(15.f, fmaxf(-15.f, v));
    float e = __expf(2.f * xc);
    return __fdividef(e - 1.f, e + 1.f);
}

__device__ __forceinline__ void load_row6(float* dst, const float* p) {
    float2 t0 = *(const float2*)(p);
    float2 t1 = *(const float2*)(p + 2);
    float2 t2 = *(const float2*)(p + 4);
    dst[0]=t0.x; dst[1]=t0.y; dst[2]=t1.x; dst[3]=t1.y; dst[4]=t2.x; dst[5]=t2.y;
}

// grouped-C3 channel tables (SL1/SL2/SL3 + full), computed arithmetically
__device__ __forceinline__ int g3_ncin(int o){ return o<6?3:(o<15?4:6); }
__device__ __forceinline__ int g3_wb(int o){ return o<6?O_FSW:(o<12?O_SCW:(o<15?O_THW:O_FOW)); }
__device__ __forceinline__ int g3_bi(int o){ return o<6?0:(o<12?1:(o<15?2:3)); }
__device__ __forceinline__ int g3_ch(int o,int j){
    if (o<6)  return (o+j)%6;                         // SL1: {i,i+1,i+2}
    if (o<12) return (o-6+j)%6;                       // SL2: {i..i+3}
    if (o<15) return (o-12 + j + (j>=2?1:0))%6;       // SL3: {i,i+1,i+3,i+4}
    return j;                                         // s4: all 6
}

__global__ __launch_bounds__(THREADS)
void lenet_fused(const float* __restrict__ x,
                 const float* __restrict__ c1_w, const float* __restrict__ c1_b,
                 const float* __restrict__ fs_w, const float* __restrict__ fs_b,
                 const float* __restrict__ sc_w, const float* __restrict__ sc_b,
                 const float* __restrict__ th_w, const float* __restrict__ th_b,
                 const float* __restrict__ fo_w, const float* __restrict__ fo_b,
                 const float* __restrict__ c5_w, const float* __restrict__ c5_b,
                 const float* __restrict__ f6_w, const float* __restrict__ f6_b,
                 const float* __restrict__ out_w, const float* __restrict__ out_b,
                 float* __restrict__ out)
{
    __shared__ float s_x[IMGS*1024];     // 32 KB, aliased by p2/c5/f6 after stage 2
    __shared__ float s_p1[IMGS*1176];    // 37.6 KB  [img][c][14][14]
    __shared__ float s_w[SW_SIZE];       // 6.6 KB packed small weights
    float* s_p2 = s_x;                         // [img][404] (400 used, pad for banks)
    float* s_c5 = s_x + IMGS*404;              // [img][120]
    float* s_f6 = s_x + IMGS*404 + IMGS*120;   // [img][84]

    const int tid = threadIdx.x;
    const int blk = blockIdx.x;

    // ---- stage 0: small weights -> LDS ----
    for (int t=tid; t<150; t+=THREADS) s_w[O_C1W+t]=c1_w[t];
    for (int t=tid; t<6;   t+=THREADS) s_w[O_C1B+t]=c1_b[t];
    for (int t=tid; t<75;  t+=THREADS) s_w[O_FSW+t]=fs_w[t];
    for (int t=tid; t<100; t+=THREADS) s_w[O_SCW+t]=sc_w[t];
    for (int t=tid; t<100; t+=THREADS) s_w[O_THW+t]=th_w[t];
    for (int t=tid; t<150; t+=THREADS) s_w[O_FOW+t]=fo_w[t];
    if (tid==0){ s_w[O_GB+0]=fs_b[0]; s_w[O_GB+1]=sc_b[0]; s_w[O_GB+2]=th_b[0]; s_w[O_GB+3]=fo_b[0]; }
    for (int t=tid; t<120; t+=THREADS) s_w[O_C5B+t]=c5_b[t];
    for (int t=tid; t<84;  t+=THREADS) s_w[O_F6B+t]=f6_b[t];
    for (int t=tid; t<840; t+=THREADS) s_w[O_OUTW+t]=out_w[t];
    for (int t=tid; t<10;  t+=THREADS) s_w[O_OUTB+t]=out_b[t];

    // ---- stage 1: x -> LDS (coalesced float4) ----
    {
        const float4* xg = (const float4*)(x + (size_t)blk*(IMGS*1024));
        float4* sx = (float4*)s_x;
        #pragma unroll
        for (int i=0;i<(IMGS*1024/4)/THREADS;i++)
            sx[tid + i*THREADS] = xg[tid + i*THREADS];
    }
    __syncthreads();

    // ---- stage 2: conv1(5x5) + tanh + 2x2 avgpool -> s_p1[img][c][14][14] ----
    // one thread = one (img,c,pw) column of 14 pooled rows; sliding 6x6 window in regs
    for (int idx=tid; idx<IMGS*84; idx+=THREADS) {
        const int img = idx/84, r2 = idx%84, c = r2/14, pw = r2%14;
        const float* xim = s_x + img*1024 + 2*pw;
        float w[25];
        #pragma unroll
        for (int k=0;k<25;k++) w[k] = s_w[O_C1W + c*25 + k];
        const float bias = s_w[O_C1B + c];
        float win[6][6];
        #pragma unroll
        for (int r=0;r<4;r++) load_row6(win[r], xim + r*32);
        float* p1o = s_p1 + img*1176 + c*196 + pw;
        #pragma unroll
        for (int ph=0; ph<14; ph++) {
            load_row6(win[(2*ph+4)%6], xim + (2*ph+4)*32);
            load_row6(win[(2*ph+5)%6], xim + (2*ph+5)*32);
            float s = 0.f;
            #pragma unroll
            for (int dy=0; dy<2; dy++)
            #pragma unroll
            for (int dx=0; dx<2; dx++) {
                float acc = bias;
                #pragma unroll
                for (int ky=0; ky<5; ky++)
                #pragma unroll
                for (int kx=0; kx<5; kx++)
                    acc = fmaf(win[(2*ph+dy+ky)%6][dx+kx], w[ky*5+kx], acc);
                s += fast_tanh(acc);
            }
            p1o[ph*14] = 0.25f*s;
        }
    }
    __syncthreads();

    // ---- stage 3: grouped C3 + tanh + 2x2 avgpool -> s_p2[img][16*5*5] ----
    // one thread = one (img,o,pw) column: 10 conv rows x 2 cols accumulators
    for (int idx=tid; idx<IMGS*80; idx+=THREADS) {
        const int img = idx/80, r2 = idx%80, o = r2/5, pw = r2%5;
        const int ncin = g3_ncin(o);
        const int wb   = g3_wb(o);
        const float bias = s_w[O_GB + g3_bi(o)];
        float acc0[10], acc1[10];
        #pragma unroll
        for (int h=0;h<10;h++){ acc0[h]=bias; acc1[h]=bias; }
        for (int j=0;j<ncin;j++) {
            const int ch = g3_ch(o,j);
            const float* p1c = s_p1 + img*1176 + ch*196 + 2*pw;
            float w[25];
            #pragma unroll
            for (int k=0;k<25;k++) w[k] = s_w[wb + j*25 + k];
            #pragma unroll
            for (int r=0;r<14;r++) {
                float row[6];
                load_row6(row, p1c + r*14);
                #pragma unroll
                for (int ky=0;ky<5;ky++) {
                    const int hh = r - ky;
                    if (hh >= 0 && hh < 10) {
                        float s0=0.f, s1=0.f;
                        #pragma unroll
                        for (int kx=0;kx<5;kx++){
                            s0 = fmaf(row[kx],   w[ky*5+kx], s0);
                            s1 = fmaf(row[kx+1], w[ky*5+kx], s1);
                        }
                        acc0[hh] += s0; acc1[hh] += s1;
                    }
                }
            }
        }
        float* p2o = s_p2 + img*404 + o*25 + pw;
        #pragma unroll
        for (int ph=0; ph<5; ph++) {
            float t = fast_tanh(acc0[2*ph])   + fast_tanh(acc1[2*ph])
                    + fast_tanh(acc0[2*ph+1]) + fast_tanh(acc1[2*ph+1]);
            p2o[ph*5] = 0.25f*t;
        }
    }
    __syncthreads();

    // ---- stage 4: conv5 = 120x400 matvec per image + tanh -> s_c5[img][120] ----
    // lanes: img minor (8) -> c5_w row shared per 8 lanes (coalesced), p2 broadcast
    for (int idx=tid; idx<120*IMGS; idx+=THREADS) {
        const int f = idx >> 3, img = idx & 7;
        const float4* wr = (const float4*)(c5_w + f*400);
        const float4* pr = (const float4*)(s_p2 + img*404);
        float a0=0.f,a1=0.f,a2=0.f,a3=0.f;
        #pragma unroll 4
        for (int k=0;k<100;k++) {
            float4 a = wr[k], b = pr[k];
            a0=fmaf(a.x,b.x,a0); a1=fmaf(a.y,b.y,a1);
            a2=fmaf(a.z,b.z,a2); a3=fmaf(a.w,b.w,a3);
        }
        s_c5[img*120 + f] = fast_tanh((a0+a1)+(a2+a3) + s_w[O_C5B + f]);
    }
    __syncthreads();

    // ---- stage 5: f6 (84x120) + tanh -> s_f6[img][84] ----
    for (int idx=tid; idx<84*IMGS; idx+=THREADS) {
        const int j = idx >> 3, img = idx & 7;
        const float4* wr = (const float4*)(f6_w + j*120);
        const float4* cr = (const float4*)(s_c5 + img*120);
        float a0=0.f,a1=0.f,a2=0.f,a3=0.f;
        #pragma unroll
        for (int k=0;k<30;k++) {
            float4 a = wr[k], b = cr[k];
            a0=fmaf(a.x,b.x,a0); a1=fmaf(a.y,b.y,a1);
            a2=fmaf(a.z,b.z,a2); a3=fmaf(a.w,b.w,a3);
        }
        s_f6[img*84 + j] = fast_tanh((a0+a1)+(a2+a3) + s_w[O_F6B + j]);
    }
    __syncthreads();

    // ---- stage 6: out (10x84) -> global ----
    if (tid < 80) {
        const int j = tid >> 3, img = tid & 7;
        const float* wr = s_w + O_OUTW + j*84;
        const float* fr = s_f6 + img*84;
        float a0=0.f,a1=0.f,a2=0.f,a3=0.f;
        #pragma unroll
        for (int k=0;k<84;k+=4) {
            a0=fmaf(wr[k],  fr[k],  a0); a1=fmaf(wr[k+1],fr[k+1],a1);
            a2=fmaf(wr[k+2],fr[k+2],a2); a3=fmaf(wr[k+3],fr[k+3],a3);
        }
        out[((size_t)blk*IMGS + img)*10 + j] = (a0+a1)+(a2+a3) + s_w[O_OUTB + j];
    }
}

extern "C" void kernel_launch(void* const* d_in, const int* in_sizes, int n_in,
                              void* d_out, int out_size, void* d_ws, size_t ws_size,
                              hipStream_t stream) {
    const float* x    = (const float*)d_in[0];
    const float* c1w  = (const float*)d_in[1];
    const float* c1b  = (const float*)d_in[2];
    const float* fsw  = (const float*)d_in[3];
    const float* fsb  = (const float*)d_in[4];
    const float* scw  = (const float*)d_in[5];
    const float* scb  = (const float*)d_in[6];
    const float* thw  = (const float*)d_in[7];
    const float* thb  = (const float*)d_in[8];
    const float* fow  = (const float*)d_in[9];
    const float* fob  = (const float*)d_in[10];
    const float* c5w  = (const float*)d_in[11];
    const float* c5b  = (const float*)d_in[12];
    const float* f6w  = (const float*)d_in[13];
    const float* f6b  = (const float*)d_in[14];
    const float* outw = (const float*)d_in[15];
    const float* outb = (const float*)d_in[16];
    float* outp = (float*)d_out;

    const int B = in_sizes[0] / 1024;     // 16384
    const int nblk = B / IMGS;            // 2048
    lenet_fused<<<nblk, THREADS, 0, stream>>>(
        x, c1w, c1b, fsw, fsb, scw, scb, thw, thb, fow, fob,
        c5w, c5b, f6w, f6b, outw, outb, outp);
}